// Round 10
// baseline (468.700 us; speedup 1.0000x reference)
//
#include <hip/hip_runtime.h>
#include <hip/hip_bf16.h>

static constexpr int H = 16;        // hidden channels
static constexpr int C = 16;        // num classes
static constexpr int MAXNB = 4096;  // max dst-buckets (N <= 65536, 16 dsts/bucket)
static constexpr int HIST_BLOCKS = 32;

// ---------------- prep: W2 -> transposed f32 [R][C][H] -----------------------------
__global__ void k0_w2t(const float* __restrict__ W2, float* __restrict__ w2t, int total) {
    int i = blockIdx.x * blockDim.x + threadIdx.x;
    if (i >= total) return;
    int r = i >> 8, kc = i & 255, k = kc >> 4, c = kc & 15;
    w2t[(r << 8) + (c << 4) + k] = W2[i];
}

// ---------------- bin phase A: per-block private histograms (no global atomics) ----
__global__ void kA_hist(const int* __restrict__ dstv, int* __restrict__ hist2d,
                        int E, int NB) {
    __shared__ int lh[MAXNB];
    for (int i = threadIdx.x; i < NB; i += blockDim.x) lh[i] = 0;
    __syncthreads();
    int qtot = (E + 3) >> 2;
    for (int q = blockIdx.x * blockDim.x + threadIdx.x; q < qtot;
         q += gridDim.x * blockDim.x) {
        int e0 = q << 2;
        if (e0 + 4 <= E) {
            int4 d = *(const int4*)(dstv + e0);
            atomicAdd(&lh[d.x >> 4], 1);
            atomicAdd(&lh[d.y >> 4], 1);
            atomicAdd(&lh[d.z >> 4], 1);
            atomicAdd(&lh[d.w >> 4], 1);
        } else {
            for (int e = e0; e < E; ++e) atomicAdd(&lh[dstv[e] >> 4], 1);
        }
    }
    __syncthreads();
    int* row = hist2d + (size_t)blockIdx.x * MAXNB;
    for (int i = threadIdx.x; i < NB; i += blockDim.x) row[i] = lh[i];
}

// ---------------- bin phase B1: column-sum the private histograms ------------------
__global__ void kB1_sum(const int* __restrict__ hist2d, int* __restrict__ cnt, int NB) {
    int i = blockIdx.x * blockDim.x + threadIdx.x;
    if (i >= NB) return;
    int a = 0;
#pragma unroll
    for (int b = 0; b < HIST_BLOCKS; ++b) a += hist2d[(size_t)b * MAXNB + i];
    cnt[i] = a;
}

// ---------------- bin phase B2: exclusive scan -> base, cursor ---------------------
__global__ void kB2_scan(const int* __restrict__ cnt, int* __restrict__ base,
                         int* __restrict__ cursor, int NB) {
    __shared__ int sh[1024];
    int t = threadIdx.x;
    int v[4]; int s = 0;
#pragma unroll
    for (int j = 0; j < 4; ++j) {
        int idx = t * 4 + j;
        v[j] = (idx < NB) ? cnt[idx] : 0;
        s += v[j];
    }
    sh[t] = s;
    __syncthreads();
    for (int off = 1; off < 1024; off <<= 1) {
        int val = (t >= off) ? sh[t - off] : 0;
        __syncthreads();
        sh[t] += val;
        __syncthreads();
    }
    int excl = sh[t] - s;
#pragma unroll
    for (int j = 0; j < 4; ++j) {
        int idx = t * 4 + j;
        if (idx < NB) { base[idx] = excl; cursor[idx] = excl; excl += v[j]; }
    }
}

// ---------------- bin phase C: fill records (et<<20 | src<<4 | dstlow) -------------
// Cursor atomics hit ~196 hot L2-resident lines; record stores land in 3125 dense
// growing regions (L2 write-merge) -- NOT the r5 random-100MB failure mode.
__global__ void kC_fill(const int* __restrict__ srcv, const int* __restrict__ dstv,
                        const int* __restrict__ etv, int* __restrict__ cursor,
                        unsigned* __restrict__ recs, int E) {
    int q = blockIdx.x * blockDim.x + threadIdx.x;
    int e0 = q << 2;
    if (e0 >= E) return;
    if (e0 + 4 <= E) {
        int4 s = *(const int4*)(srcv + e0);
        int4 d = *(const int4*)(dstv + e0);
        int4 r = *(const int4*)(etv + e0);
        int p;
        p = atomicAdd(&cursor[d.x >> 4], 1); recs[p] = ((unsigned)r.x << 20) | ((unsigned)s.x << 4) | (unsigned)(d.x & 15);
        p = atomicAdd(&cursor[d.y >> 4], 1); recs[p] = ((unsigned)r.y << 20) | ((unsigned)s.y << 4) | (unsigned)(d.y & 15);
        p = atomicAdd(&cursor[d.z >> 4], 1); recs[p] = ((unsigned)r.z << 20) | ((unsigned)s.z << 4) | (unsigned)(d.z & 15);
        p = atomicAdd(&cursor[d.w >> 4], 1); recs[p] = ((unsigned)r.w << 20) | ((unsigned)s.w << 4) | (unsigned)(d.w & 15);
    } else {
        for (int e = e0; e < E; ++e) {
            int p = atomicAdd(&cursor[dstv[e] >> 4], 1);
            recs[p] = ((unsigned)etv[e] << 20) | ((unsigned)srcv[e] << 4) | (unsigned)(dstv[e] & 15);
        }
    }
}

// ---------------- Layer 1 (pull): h1 = relu(root1 + sum W1[et,src] + bias1) --------
// One block per 16-dst bucket; f32 accumulation in a 1KB LDS window (ds_add_f32);
// one coalesced store per bucket. Zero global atomics.
__global__ void k1p(const unsigned* __restrict__ recs, const int* __restrict__ base,
                    const int* __restrict__ cnt, const float* __restrict__ W1,
                    const float* __restrict__ root1, const float* __restrict__ bias1,
                    float* __restrict__ h1, int N) {
    __shared__ float win[256];
    int b = blockIdx.x;
    win[threadIdx.x] = 0.f;
    __syncthreads();
    int st = base[b], n = cnt[b];
    int g = threadIdx.x >> 4, c = threadIdx.x & 15;
    for (int i = g; i < n; i += 16) {
        unsigned rec = recs[st + i];             // broadcast across the 16-lane group
        int et = rec >> 20;
        int src = (rec >> 4) & 0xFFFF;
        int dl = rec & 15;
        float w = W1[(((size_t)et * N + src) << 4) + c];   // coalesced 64B per group
        atomicAdd(&win[(dl << 4) + c], w);       // ds_add_f32
    }
    __syncthreads();
    int d = (b << 4) + g;
    if (d < N) {
        float val = win[threadIdx.x] + root1[(d << 4) + c] + bias1[c];
        h1[((size_t)d << 4) + c] = fmaxf(val, 0.f);
    }
}

// ---------------- Layer 2 (pull) + fused root2 matvec + log_softmax ----------------
__global__ void k3p(const unsigned* __restrict__ recs, const int* __restrict__ base,
                    const int* __restrict__ cnt, const float* __restrict__ h1,
                    const float* __restrict__ w2t, const float* __restrict__ root2,
                    const float* __restrict__ bias2, float* __restrict__ out, int N) {
    __shared__ float win[256];
    int b = blockIdx.x;
    win[threadIdx.x] = 0.f;
    __syncthreads();
    int st = base[b], n = cnt[b];
    int g = threadIdx.x >> 4, c = threadIdx.x & 15;
    for (int i = g; i < n; i += 16) {
        unsigned rec = recs[st + i];
        int et = rec >> 20;
        int src = (rec >> 4) & 0xFFFF;
        int dl = rec & 15;
        const float4* hp = (const float4*)(h1 + ((size_t)src << 4));   // 64B broadcast
        float4 h0 = hp[0], h1v = hp[1], h2v = hp[2], h3v = hp[3];
        const float4* wp = (const float4*)(w2t + (et << 8) + (c << 4)); // L1-resident
        float4 w0 = wp[0], w1 = wp[1], w2v = wp[2], w3 = wp[3];
        float acc = h0.x * w0.x + h0.y * w0.y + h0.z * w0.z + h0.w * w0.w
                  + h1v.x * w1.x + h1v.y * w1.y + h1v.z * w1.z + h1v.w * w1.w
                  + h2v.x * w2v.x + h2v.y * w2v.y + h2v.z * w2v.z + h2v.w * w2v.w
                  + h3v.x * w3.x + h3v.y * w3.y + h3v.z * w3.z + h3v.w * w3.w;
        atomicAdd(&win[(dl << 4) + c], acc);     // ds_add_f32
    }
    __syncthreads();
    int d = (b << 4) + g;
    if (d >= N) return;                          // whole 16-lane groups exit together
    const float* hd = h1 + ((size_t)d << 4);
    float z = win[threadIdx.x] + bias2[c];
#pragma unroll
    for (int k = 0; k < 16; ++k) z += hd[k] * root2[(k << 4) + c];
    float m = z;
#pragma unroll
    for (int off = 8; off; off >>= 1) m = fmaxf(m, __shfl_xor(m, off, 16));
    float ex = __expf(z - m), se = ex;
#pragma unroll
    for (int off = 8; off; off >>= 1) se += __shfl_xor(se, off, 16);
    out[((size_t)d << 4) + c] = z - m - __logf(se);
}

extern "C" void kernel_launch(void* const* d_in, const int* in_sizes, int n_in,
                              void* d_out, int out_size, void* d_ws, size_t ws_size,
                              hipStream_t stream) {
    const int*   edge_index = (const int*)d_in[0];
    const float* W1    = (const float*)d_in[3];
    const float* root1 = (const float*)d_in[4];
    const float* bias1 = (const float*)d_in[5];
    const float* W2    = (const float*)d_in[6];
    const float* root2 = (const float*)d_in[7];
    const float* bias2 = (const float*)d_in[8];
    float* out = (float*)d_out;

    const int E = in_sizes[0] / 2;
    const int N = in_sizes[4] / H;           // root1 is N*H
    const int R = in_sizes[2] / 2;           // tensor_slice is [R][2]
    const int NB = (N + 15) >> 4;            // 16 dsts per bucket
    const int* srcv = edge_index;
    const int* dstv = edge_index + E;
    const int* etv  = (const int*)d_in[1];

    // ws: recs u32[E] | h1 f32[N*16] | w2t f32[R*256] | hist2d int[32*MAXNB]
    //     | cnt[NB] | base[NB] | cursor[NB]
    char* p = (char*)d_ws;
    unsigned* recs = (unsigned*)p;        p += (size_t)E * 4;
    float* h1 = (float*)p;                p += (size_t)N * 16 * 4;
    float* w2t = (float*)p;               p += (size_t)R * 256 * 4;
    int* hist2d = (int*)p;                p += (size_t)HIST_BLOCKS * MAXNB * 4;
    int* cnt = (int*)p;                   p += (size_t)NB * 4;
    int* base = (int*)p;                  p += (size_t)NB * 4;
    int* cursor = (int*)p;

    const int B = 256;
    k0_w2t<<<(R * 256 + B - 1) / B, B, 0, stream>>>(W2, w2t, R * 256);
    kA_hist<<<HIST_BLOCKS, B, 0, stream>>>(dstv, hist2d, E, NB);
    kB1_sum<<<(NB + B - 1) / B, B, 0, stream>>>(hist2d, cnt, NB);
    kB2_scan<<<1, 1024, 0, stream>>>(cnt, base, cursor, NB);
    int qtot = (E + 3) / 4;
    kC_fill<<<(qtot + B - 1) / B, B, 0, stream>>>(srcv, dstv, etv, cursor, recs, E);
    k1p<<<NB, B, 0, stream>>>(recs, base, cnt, W1, root1, bias1, h1, N);
    k3p<<<NB, B, 0, stream>>>(recs, base, cnt, h1, w2t, root2, bias2, out, N);
}

// Round 11
// 182.926 us; speedup vs baseline: 2.5622x; 2.5622x over previous
//
#include <hip/hip_runtime.h>
#include <hip/hip_bf16.h>

static constexpr int H = 16;   // hidden channels
static constexpr int C = 16;   // num classes

typedef __attribute__((ext_vector_type(8))) short bf16x8;
typedef __attribute__((ext_vector_type(4))) float f32x4;

static __device__ inline unsigned short f2bf(float x) {
    __hip_bfloat16 b = __float2bfloat16(x);
    return *reinterpret_cast<unsigned short*>(&b);
}
static __device__ inline float bflo(unsigned u) { return __uint_as_float(u << 16); }
static __device__ inline float bfhi(unsigned u) { return __uint_as_float(u & 0xffff0000u); }
// packed bf16 atomic add (2 channels per dword)
static __device__ inline void pk_atomic_bf16(unsigned short* addr, unsigned pk) {
    asm volatile("global_atomic_pk_add_bf16 %0, %1, off" :: "v"(addr), "v"(pk) : "memory");
}
// relu on two packed bf16 (exact, bit ops only)
static __device__ inline unsigned relu_pk2(unsigned u) {
    unsigned lo = (u & 0x8000u) ? 0u : (u & 0x0000ffffu);
    unsigned hi = (u & 0x80000000u) ? 0u : (u & 0xffff0000u);
    return lo | hi;
}
static __device__ inline bf16x8 relu_bf16x8(uint4 u) {
    u.x = relu_pk2(u.x); u.y = relu_pk2(u.y);
    u.z = relu_pk2(u.z); u.w = relu_pk2(u.w);
    union { uint4 u4; bf16x8 v; } cv; cv.u4 = u;
    return cv.v;
}

// ---------------- fused prep: acc1=bf16(root1+bias1) | zero acc2 | W2 cast | cmap --
__global__ void k0_fused(const float* __restrict__ W2, const int* __restrict__ ts,
                         const float* __restrict__ root1, const float* __restrict__ bias1,
                         unsigned short* __restrict__ acc1, unsigned short* __restrict__ acc2,
                         unsigned short* __restrict__ w2t,
                         int* __restrict__ cmap_e0, int* __restrict__ cmap_rn,
                         int N, int R, int UB) {
    int t = blockIdx.x * blockDim.x + threadIdx.x;
    if (t < 4 * N) {
        float4 rv = ((const float4*)root1)[t];
        float4 bv = ((const float4*)bias1)[t & 3];
        uint2 p;
        p.x = ((unsigned)f2bf(rv.y + bv.y) << 16) | f2bf(rv.x + bv.x);
        p.y = ((unsigned)f2bf(rv.w + bv.w) << 16) | f2bf(rv.z + bv.z);
        ((uint2*)acc1)[t] = p;
        return;
    }
    t -= 4 * N;
    if (t < 2 * N) {
        ((uint4*)acc2)[t] = make_uint4(0u, 0u, 0u, 0u);
        return;
    }
    t -= 2 * N;
    if (t < R * 256) {
        int r = t >> 8;
        int kc = t & 255;
        int k = kc >> 4, c = kc & 15;
        w2t[(r << 8) + (c << 4) + k] = f2bf(W2[t]);
        return;
    }
    t -= R * 256;
    if (t >= UB) return;
    int cacc = 0, my_e0 = 0, my_rn = 0;
    for (int r = 0; r < R; ++r) {
        int b = ts[2 * r], e = ts[2 * r + 1];
        int nc = (e - b + 15) >> 4;
        if (t >= cacc && t < cacc + nc) {
            int e0 = b + ((t - cacc) << 4);
            my_e0 = e0;
            my_rn = (min(16, e - e0) << 8) | r;
        }
        cacc += nc;
    }
    cmap_e0[t] = my_e0;
    cmap_rn[t] = my_rn;     // n=0 for invalid chunks -> k3 skips their atomics
}

// ---------------- Layer 1: acc1[dst] += bf16x2(W1[et, src]) ------------------------
// 8 lanes x 8 edges per group, ONE pk atomic per edge per lane (one instruction
// covers the full 32B row via 8 lanes). XCD-chunked block swizzle for gather L2
// locality (halves FETCH; atomic wall unaffected).
__global__ void k1_scatter(const int* __restrict__ srcv, const int* __restrict__ dstv,
                           const int* __restrict__ etv, const float* __restrict__ W1,
                           unsigned short* __restrict__ acc1, int E, int N, int nblk8) {
    int b = blockIdx.x;
    int q = nblk8 >> 3;
    int sb = (b & 7) * q + (b >> 3);          // bijective: nblk8 is a multiple of 8
    int t = sb * 256 + (int)threadIdx.x;
    int g = t >> 3;            // group of 8 lanes handles 8 edges
    int cp = t & 7;            // channel pair: channels 2cp, 2cp+1
    int e0 = g << 3;
    if (e0 >= E) return;
    int s[8], d[8], r[8];
    int n;
    if (e0 + 8 <= E) {
        n = 8;
        int4 s0 = *(const int4*)(srcv + e0), s1 = *(const int4*)(srcv + e0 + 4);
        int4 d0 = *(const int4*)(dstv + e0), d1 = *(const int4*)(dstv + e0 + 4);
        int4 r0 = *(const int4*)(etv + e0),  r1 = *(const int4*)(etv + e0 + 4);
        s[0]=s0.x; s[1]=s0.y; s[2]=s0.z; s[3]=s0.w; s[4]=s1.x; s[5]=s1.y; s[6]=s1.z; s[7]=s1.w;
        d[0]=d0.x; d[1]=d0.y; d[2]=d0.z; d[3]=d0.w; d[4]=d1.x; d[5]=d1.y; d[6]=d1.z; d[7]=d1.w;
        r[0]=r0.x; r[1]=r0.y; r[2]=r0.z; r[3]=r0.w; r[4]=r1.x; r[5]=r1.y; r[6]=r1.z; r[7]=r1.w;
    } else {
        n = E - e0;
#pragma unroll
        for (int i = 0; i < 8; ++i) {
            int e = e0 + ((i < n) ? i : 0);
            s[i] = srcv[e]; d[i] = dstv[e]; r[i] = etv[e];
        }
    }
    float2 v[8];
#pragma unroll
    for (int i = 0; i < 8; ++i) {
        unsigned off = ((unsigned)(r[i] * N + s[i]) << 4) + ((unsigned)cp << 1);
        v[i] = *(const float2*)(W1 + off);
    }
#pragma unroll
    for (int i = 0; i < 8; ++i) {
        if (i < n) {
            unsigned pk = ((unsigned)f2bf(v[i].y) << 16) | f2bf(v[i].x);
            pk_atomic_bf16(acc1 + ((size_t)d[i] << 4) + (cp << 1), pk);
        }
    }
}

// ---------------- Layer 2 via MFMA: one wave = 4 chunks (64 edges) -----------------
// h1 = relu(acc1) applied inline on load (k2 fused away).
__global__ void k3_mfma(const int* __restrict__ srcv, const int* __restrict__ dstv,
                        const int* __restrict__ cmap_e0, const int* __restrict__ cmap_rn,
                        const unsigned short* __restrict__ acc1,
                        const unsigned short* __restrict__ w2t,
                        unsigned short* __restrict__ acc2, int UB) {
    int w = (blockIdx.x * blockDim.x + threadIdx.x) >> 6;
    int l = threadIdx.x & 63;
    int c0 = w << 2;
    if (c0 >= UB) return;
    int rowA = l & 15;
    int kg = l >> 4;

    int e0[4], rr[4], nn[4];
#pragma unroll
    for (int q = 0; q < 4; ++q) {
        int cq = c0 + q;
        bool ok = cq < UB;
        e0[q] = ok ? cmap_e0[cq] : 0;
        int rn = ok ? cmap_rn[cq] : 0;
        rr[q] = rn & 255;
        nn[q] = rn >> 8;            // 0 -> chunk produces no atomics
    }
    __builtin_amdgcn_sched_barrier(0);
    int s[4], dd[4];
#pragma unroll
    for (int q = 0; q < 4; ++q) {
        int eA = e0[q] + max(0, min(rowA, nn[q] - 1));
        s[q] = srcv[eA];
        dd[q] = dstv[eA];           // lane rowA holds row rowA's dst
    }
    __builtin_amdgcn_sched_barrier(0);
    bf16x8 a[4], b[4];
#pragma unroll
    for (int q = 0; q < 4; ++q) {
        bf16x8 z = {0, 0, 0, 0, 0, 0, 0, 0};
        a[q] = z; b[q] = z;
        if (kg < 2) {
            uint4 raw = *(const uint4*)(acc1 + ((size_t)s[q] << 4) + (kg << 3));
            a[q] = relu_bf16x8(raw);                       // h1 = relu(acc1), inline
            b[q] = *(const bf16x8*)(w2t + ((size_t)rr[q] << 8) + (rowA << 4) + (kg << 3));
        }
    }
    __builtin_amdgcn_sched_barrier(0);
    f32x4 d[4];
#pragma unroll
    for (int q = 0; q < 4; ++q) {
        f32x4 z4 = {0.f, 0.f, 0.f, 0.f};
        d[q] = __builtin_amdgcn_mfma_f32_16x16x32_bf16(a[q], b[q], z4, 0, 0, 0);
    }
    int c = l & 15;
#pragma unroll
    for (int q = 0; q < 4; ++q) {
#pragma unroll
        for (int j = 0; j < 4; ++j) {
            int row = (kg << 2) + j;
            float o = __shfl_xor(d[q][j], 1);          // neighbor column, same row
            int ddv = __shfl(dd[q], row);              // dst of this row
            if (((l & 1) == 0) && row < nn[q]) {
                unsigned pk = ((unsigned)f2bf(o) << 16) | f2bf(d[q][j]);
                pk_atomic_bf16(acc2 + ((size_t)ddv << 4) + c, pk);
            }
        }
    }
}

// ---------------- h2 = relu(acc1) @ root2 + acc2 + bias2; row log_softmax ----------
__global__ void k4_fin2(const unsigned short* __restrict__ acc1,
                        const unsigned short* __restrict__ acc2,
                        const float* __restrict__ root2, const float* __restrict__ bias2,
                        float* __restrict__ out, int N) {
    int n = blockIdx.x * blockDim.x + threadIdx.x;
    if (n >= N) return;
    const uint4* hp = (const uint4*)(acc1 + (size_t)n * 16);
    uint4 h0 = hp[0], h1 = hp[1];
    h0.x = relu_pk2(h0.x); h0.y = relu_pk2(h0.y); h0.z = relu_pk2(h0.z); h0.w = relu_pk2(h0.w);
    h1.x = relu_pk2(h1.x); h1.y = relu_pk2(h1.y); h1.z = relu_pk2(h1.z); h1.w = relu_pk2(h1.w);
    float h[16] = {bflo(h0.x), bfhi(h0.x), bflo(h0.y), bfhi(h0.y),
                   bflo(h0.z), bfhi(h0.z), bflo(h0.w), bfhi(h0.w),
                   bflo(h1.x), bfhi(h1.x), bflo(h1.y), bfhi(h1.y),
                   bflo(h1.z), bfhi(h1.z), bflo(h1.w), bfhi(h1.w)};
    const uint4* ap = (const uint4*)(acc2 + (size_t)n * 16);
    uint4 a0 = ap[0], a1 = ap[1];
    float av[16] = {bflo(a0.x), bfhi(a0.x), bflo(a0.y), bfhi(a0.y),
                    bflo(a0.z), bfhi(a0.z), bflo(a0.w), bfhi(a0.w),
                    bflo(a1.x), bfhi(a1.x), bflo(a1.y), bfhi(a1.y),
                    bflo(a1.z), bfhi(a1.z), bflo(a1.w), bfhi(a1.w)};
    float* o = out + (size_t)n * C;
    float z[16];
#pragma unroll
    for (int c = 0; c < 16; ++c) {
        float acc = av[c] + bias2[c];
#pragma unroll
        for (int k = 0; k < 16; ++k) acc += h[k] * root2[k * C + c];
        z[c] = acc;
    }
    float m = z[0];
#pragma unroll
    for (int c = 1; c < 16; ++c) m = fmaxf(m, z[c]);
    float se = 0.f;
#pragma unroll
    for (int c = 0; c < 16; ++c) se += __expf(z[c] - m);
    float lse = m + __logf(se);
#pragma unroll
    for (int c = 0; c < 16; ++c) o[c] = z[c] - lse;
}

extern "C" void kernel_launch(void* const* d_in, const int* in_sizes, int n_in,
                              void* d_out, int out_size, void* d_ws, size_t ws_size,
                              hipStream_t stream) {
    const int*   edge_index   = (const int*)d_in[0];
    const int*   edge_type    = (const int*)d_in[1];
    const int*   tensor_slice = (const int*)d_in[2];
    const float* W1    = (const float*)d_in[3];
    const float* root1 = (const float*)d_in[4];
    const float* bias1 = (const float*)d_in[5];
    const float* W2    = (const float*)d_in[6];
    const float* root2 = (const float*)d_in[7];
    const float* bias2 = (const float*)d_in[8];
    float* out = (float*)d_out;

    const int E = in_sizes[0] / 2;
    const int N = in_sizes[4] / H;           // root1 is N*H
    const int R = in_sizes[2] / 2;           // tensor_slice is [R][2]
    const int* srcv = edge_index;
    const int* dstv = edge_index + E;

    // ws: acc1 bf16[N*16] | acc2 bf16[N*16] | w2t u16[R*256] | cmap_e0[UB] | cmap_rn[UB]
    const int UB = (E + 15) / 16 + R;        // upper bound on chunk count
    char* p = (char*)d_ws;
    unsigned short* acc1 = (unsigned short*)p;   p += (size_t)N * 16 * 2;
    unsigned short* acc2 = (unsigned short*)p;   p += (size_t)N * 16 * 2;
    unsigned short* w2t = (unsigned short*)p;    p += (size_t)R * 256 * 2;
    int* cmap_e0 = (int*)p;                      p += (size_t)UB * 4;
    int* cmap_rn = (int*)p;

    const int B = 256;
    // fused prep: init acc1 with root1+bias1, zero acc2, cast W2, build chunk map
    int prep_threads = 6 * N + R * 256 + UB;
    k0_fused<<<(prep_threads + B - 1) / B, B, 0, stream>>>(W2, tensor_slice, root1, bias1,
                                                           acc1, acc2, w2t,
                                                           cmap_e0, cmap_rn, N, R, UB);
    // layer 1: 8 lanes x 8 edges per group, XCD-chunked swizzle (grid padded to x8)
    long long t1 = (((long long)E + 7) / 8) * 8;
    int nblk1 = (int)((t1 + B - 1) / B);
    nblk1 = (nblk1 + 7) & ~7;
    k1_scatter<<<nblk1, B, 0, stream>>>(srcv, dstv, edge_type, W1, acc1, E, N, nblk1);
    // layer 2: 4 chunks per wave, relu fused into A-fragment load
    long long waves = ((long long)UB + 3) / 4;
    long long thr = waves * 64;
    k3_mfma<<<(int)((thr + B - 1) / B), B, 0, stream>>>(srcv, dstv, cmap_e0, cmap_rn,
                                                        acc1, w2t, acc2, UB);
    k4_fin2<<<(N + B - 1) / B, B, 0, stream>>>(acc1, acc2, root2, bias2, out, N);
}